// Round 5
// baseline (263.035 us; speedup 1.0000x reference)
//
#include <hip/hip_runtime.h>

#define BH_ 32
#define S_ 2048
#define D_ 64
#define DQK 128
#define BQ 128   // q rows per block (4 waves x 32 q-rows each)
#define BK 64    // kv rows per tile

typedef unsigned short u16;
typedef u16 u16x4 __attribute__((ext_vector_type(4)));
typedef u16 u16x8 __attribute__((ext_vector_type(8)));
typedef __bf16 bf16x8 __attribute__((ext_vector_type(8)));
typedef float f32x4 __attribute__((ext_vector_type(4)));

__device__ __forceinline__ u16 f2bf_rne(float f) {
  unsigned u = __builtin_bit_cast(unsigned, f);
  u += 0x7fffu + ((u >> 16) & 1u);
  return (u16)(u >> 16);
}
__device__ __forceinline__ u16 f2bf_fast(float f) {  // round-half-up
  unsigned u = __builtin_bit_cast(unsigned, f);
  u += 0x8000u;
  return (u16)(u >> 16);
}
__device__ __forceinline__ bf16x8 ld8(const u16* p) {
  return __builtin_bit_cast(bf16x8, *(const u16x8*)p);
}

// LDS-only barrier: does NOT drain vmcnt -> prefetch global loads stay in flight
#define BARRIER_LGKM() asm volatile("s_waitcnt lgkmcnt(0)\n\ts_barrier" ::: "memory")

#define COEF 0.1803368801111204f  // (1/8) * log2(e), folded into Q conversion

// ---------------- prep: Kc = bf16 [K|Kp] concat; Vt = bf16 V-transposed ----
__global__ __launch_bounds__(256)
void prep_kernel(const float* __restrict__ K, const float* __restrict__ V,
                 const float* __restrict__ Kp,
                 u16* __restrict__ Kc, u16* __restrict__ Vt) {
  __shared__ float Ls[64][65];
  int b = blockIdx.x;
  if (b < 4096) {
    int t = b * 256 + threadIdx.x;          // 1,048,576 threads x 8 elems
    int col8 = (t & 15) * 8;
    int s    = (t >> 4) & 2047;
    int bh   = t >> 15;
    const float* src = (col8 < 64) ? (K  + ((size_t)bh * S_ + s) * D_ + col8)
                                   : (Kp + ((size_t)bh * S_ + s) * D_ + (col8 - 64));
    float4 v0 = *(const float4*)src;
    float4 v1 = *(const float4*)(src + 4);
    u16x8 w;
    w[0] = f2bf_rne(v0.x); w[1] = f2bf_rne(v0.y); w[2] = f2bf_rne(v0.z); w[3] = f2bf_rne(v0.w);
    w[4] = f2bf_rne(v1.x); w[5] = f2bf_rne(v1.y); w[6] = f2bf_rne(v1.z); w[7] = f2bf_rne(v1.w);
    *(u16x8*)(Kc + ((size_t)bh * S_ + s) * DQK + col8) = w;
  } else {
    int id = b - 4096;
    int bh = id >> 5, kt = id & 31;
    int tid = threadIdx.x;
    #pragma unroll
    for (int it = 0; it < 4; ++it) {
      int i = it * 256 + tid;
      int kv = i >> 4, dg = (i & 15) * 4;
      float4 v = *(const float4*)(V + ((size_t)bh * S_ + kt * 64 + kv) * D_ + dg);
      Ls[kv][dg + 0] = v.x; Ls[kv][dg + 1] = v.y;
      Ls[kv][dg + 2] = v.z; Ls[kv][dg + 3] = v.w;
    }
    __syncthreads();
    int d = tid >> 2, kvg = (tid & 3) * 16;
    u16x8 w0, w1;
    #pragma unroll
    for (int j = 0; j < 8; ++j) w0[j] = f2bf_rne(Ls[kvg + j][d]);
    #pragma unroll
    for (int j = 0; j < 8; ++j) w1[j] = f2bf_rne(Ls[kvg + 8 + j][d]);
    u16* dst = Vt + (((size_t)bh * 32 + kt) * 64 + d) * 64 + kvg;
    *(u16x8*)dst = w0;
    *(u16x8*)(dst + 8) = w1;
  }
}

// ---------------- flash-attention main kernel -----------------------------
// S^T = Kc.Qc^T (Q as register-held B operand). XOR-swizzled unpadded LDS
// (40960 B -> 3 blocks/CU). Register prefetch of next K/V tile; barriers
// drain lgkmcnt only so prefetch loads stay in flight. SPLIT=2 kv-halves.
template <int SPLIT>
__global__ __launch_bounds__(256, 3)
void fa5_kernel(const float* __restrict__ Q, const float* __restrict__ Qp,
                const u16* __restrict__ Kc, const u16* __restrict__ Vtg,
                float* __restrict__ out, float* __restrict__ Opart,
                float* __restrict__ lpart) {
  __shared__ alignas(16) u16 Ks[64 * 128];   // row*128 + ((ch^(row&15))*8)
  __shared__ alignas(16) u16 Vt[64 * 64];    // row*64  + ((ch^(row&7))*8)
  __shared__ alignas(16) u16 Ps[128 * 64];   // row*64  + ((ch^(row&7))*8)

  const int tid  = threadIdx.x;
  const int wave = tid >> 6;
  const int lane = tid & 63;
  const int quad = lane >> 4;
  const int l16  = lane & 15;
  const int m0   = wave * 32;

  const int bh = blockIdx.y;
  const int q0 = blockIdx.x * BQ;
  const int kz = SPLIT ? blockIdx.z : 0;
  const int kt_b = SPLIT ? kz * 16 : 0;
  const int kt_e = SPLIT ? kt_b + 16 : 32;

  // ---- Q B-frags in registers, softmax scale folded into the conversion ----
  bf16x8 bq[2][4];
  #pragma unroll
  for (int nq = 0; nq < 2; ++nq)
    #pragma unroll
    for (int ks = 0; ks < 4; ++ks) {
      const float* base = (ks < 2 ? Q : Qp)
          + ((size_t)bh * S_ + q0 + m0 + nq * 16 + l16) * D_ + (ks & 1) * 32 + quad * 8;
      float4 v0 = *(const float4*)base;
      float4 v1 = *(const float4*)(base + 4);
      u16x8 w;
      w[0] = f2bf_rne(v0.x * COEF); w[1] = f2bf_rne(v0.y * COEF);
      w[2] = f2bf_rne(v0.z * COEF); w[3] = f2bf_rne(v0.w * COEF);
      w[4] = f2bf_rne(v1.x * COEF); w[5] = f2bf_rne(v1.y * COEF);
      w[6] = f2bf_rne(v1.z * COEF); w[7] = f2bf_rne(v1.w * COEF);
      bq[nq][ks] = __builtin_bit_cast(bf16x8, w);
    }

  f32x4 acc[2][4];
  float l_part[2] = {0.f, 0.f};
  #pragma unroll
  for (int mtq = 0; mtq < 2; ++mtq)
    #pragma unroll
    for (int nt = 0; nt < 4; ++nt) acc[mtq][nt] = (f32x4){0.f, 0.f, 0.f, 0.f};

  // thread-constant staging decode
  const int krow0 = tid >> 4,  kch = tid & 15;   // K: rows krow0, +16,+32,+48
  const int vrow0 = tid >> 3,  vch = tid & 7;    // V: rows vrow0, +32

  auto load_tile = [&](int kt, u16x8 (&kb)[4], u16x8 (&vb)[2]) {
    const u16* kp = Kc + ((size_t)bh * S_ + kt * 64 + krow0) * DQK + kch * 8;
    #pragma unroll
    for (int it = 0; it < 4; ++it) kb[it] = *(const u16x8*)(kp + it * 16 * DQK);
    const u16* vp = Vtg + (((size_t)bh * 32 + kt) * 64 + vrow0) * 64 + vch * 8;
    #pragma unroll
    for (int it = 0; it < 2; ++it) vb[it] = *(const u16x8*)(vp + it * 32 * 64);
  };

  auto compute_tile = [&]() {
    // ---- S^T = Ks . Qc^T : m = kv (4 x 16), n = q (2 x 16 per wave) ----
    #pragma unroll
    for (int mt = 0; mt < 4; ++mt) {
      f32x4 s0 = (f32x4){0.f, 0.f, 0.f, 0.f};
      f32x4 s1 = (f32x4){0.f, 0.f, 0.f, 0.f};
      #pragma unroll
      for (int ks = 0; ks < 4; ++ks) {
        bf16x8 ak = ld8(&Ks[(mt * 16 + l16) * 128 + (((ks * 4 + quad) ^ l16) << 3)]);
        s0 = __builtin_amdgcn_mfma_f32_16x16x32_bf16(ak, bq[0][ks], s0, 0, 0, 0);
        s1 = __builtin_amdgcn_mfma_f32_16x16x32_bf16(ak, bq[1][ks], s1, 0, 0, 0);
      }
      u16x4 w0, w1;
      float rs0 = 0.f, rs1 = 0.f;
      #pragma unroll
      for (int r = 0; r < 4; ++r) {
        float p0 = exp2f(s0[r]);
        float p1 = exp2f(s1[r]);
        w0[r] = f2bf_fast(p0); w1[r] = f2bf_fast(p1);
        rs0 += p0; rs1 += p1;
      }
      l_part[0] += rs0; l_part[1] += rs1;
      const int chs = ((mt * 2 + (quad >> 1)) ^ (l16 & 7)) << 3;
      const int sub = (quad & 1) << 2;
      *(u16x4*)&Ps[((m0 + l16) << 6) + chs + sub]      = w0;
      *(u16x4*)&Ps[((m0 + 16 + l16) << 6) + chs + sub] = w1;
    }
    // ---- O += P . V ----
    bf16x8 pa[2][2];
    #pragma unroll
    for (int mtq = 0; mtq < 2; ++mtq)
      #pragma unroll
      for (int ks = 0; ks < 2; ++ks)
        pa[mtq][ks] = ld8(&Ps[((m0 + mtq * 16 + l16) << 6) + (((ks * 4 + quad) ^ (l16 & 7)) << 3)]);
    #pragma unroll
    for (int ntd = 0; ntd < 4; ++ntd) {
      #pragma unroll
      for (int ks = 0; ks < 2; ++ks) {
        bf16x8 bv = ld8(&Vt[((ntd * 16 + l16) << 6) + (((ks * 4 + quad) ^ (l16 & 7)) << 3)]);
        acc[0][ntd] = __builtin_amdgcn_mfma_f32_16x16x32_bf16(pa[0][ks], bv, acc[0][ntd], 0, 0, 0);
        acc[1][ntd] = __builtin_amdgcn_mfma_f32_16x16x32_bf16(pa[1][ks], bv, acc[1][ntd], 0, 0, 0);
      }
    }
  };

  auto step = [&](int kt, u16x8 (&kcur)[4], u16x8 (&vcur)[2],
                  u16x8 (&knxt)[4], u16x8 (&vnxt)[2]) {
    // write staged regs -> LDS (auto vmcnt waits only on kcur/vcur data deps)
    #pragma unroll
    for (int it = 0; it < 4; ++it) {
      int row = krow0 + it * 16;
      *(u16x8*)&Ks[row * 128 + ((kch ^ (row & 15)) << 3)] = kcur[it];
    }
    #pragma unroll
    for (int it = 0; it < 2; ++it) {
      int row = vrow0 + it * 32;
      *(u16x8*)&Vt[(row << 6) + ((vch ^ (row & 7)) << 3)] = vcur[it];
    }
    if (kt + 1 < kt_e) load_tile(kt + 1, knxt, vnxt);  // prefetch, stays in flight
    BARRIER_LGKM();   // stage visible to all waves
    compute_tile();
    BARRIER_LGKM();   // all reads done before next overwrite
  };

  u16x8 kb0[4], kb1[4];
  u16x8 vb0[2], vb1[2];
  load_tile(kt_b, kb0, vb0);
  for (int kt = kt_b; kt < kt_e; kt += 2) {
    step(kt, kb0, vb0, kb1, vb1);
    if (kt + 1 < kt_e) step(kt + 1, kb1, vb1, kb0, vb0);
  }

  // ---- epilogue ----
  float lsum[2];
  #pragma unroll
  for (int nq = 0; nq < 2; ++nq) {
    float v = l_part[nq];
    v += __shfl_xor(v, 16);
    v += __shfl_xor(v, 32);
    lsum[nq] = v;  // lane holds l for q = nq*16 + l16 (this block's kv range)
  }

  if (SPLIT) {
    #pragma unroll
    for (int mtq = 0; mtq < 2; ++mtq)
      #pragma unroll
      for (int r = 0; r < 4; ++r) {
        size_t rowb = ((size_t)kz * 65536 + (size_t)bh * S_
                       + q0 + m0 + mtq * 16 + quad * 4 + r) * D_;
        #pragma unroll
        for (int ntd = 0; ntd < 4; ++ntd)
          Opart[rowb + ntd * 16 + l16] = acc[mtq][ntd][r];
      }
    if (quad == 0) {
      #pragma unroll
      for (int nq = 0; nq < 2; ++nq)
        lpart[(size_t)kz * 65536 + (size_t)bh * S_ + q0 + m0 + nq * 16 + l16] = lsum[nq];
    }
  } else {
    #pragma unroll
    for (int mtq = 0; mtq < 2; ++mtq)
      #pragma unroll
      for (int r = 0; r < 4; ++r) {
        float inv = 1.0f / __shfl(lsum[mtq], quad * 4 + r);
        size_t rowb = ((size_t)bh * S_ + q0 + m0 + mtq * 16 + quad * 4 + r) * D_;
        #pragma unroll
        for (int ntd = 0; ntd < 4; ++ntd)
          out[rowb + ntd * 16 + l16] = acc[mtq][ntd][r] * inv;
      }
  }
}

// ---------------- combine: out = (O0 + O1) / (l0 + l1) --------------------
__global__ __launch_bounds__(256)
void combine_kernel(const float* __restrict__ Opart, const float* __restrict__ lpart,
                    float* __restrict__ out) {
  int t = blockIdx.x * 256 + threadIdx.x;   // 1,048,576 threads
  int row = t >> 4;
  int d4  = (t & 15) * 4;
  const size_t NO = (size_t)65536 * D_;
  float4 o0 = *(const float4*)(Opart + (size_t)row * D_ + d4);
  float4 o1 = *(const float4*)(Opart + NO + (size_t)row * D_ + d4);
  float inv = 1.0f / (lpart[row] + lpart[65536 + row]);
  float4 o;
  o.x = (o0.x + o1.x) * inv; o.y = (o0.y + o1.y) * inv;
  o.z = (o0.z + o1.z) * inv; o.w = (o0.w + o1.w) * inv;
  *(float4*)(out + (size_t)row * D_ + d4) = o;
}

extern "C" void kernel_launch(void* const* d_in, const int* in_sizes, int n_in,
                              void* d_out, int out_size, void* d_ws, size_t ws_size,
                              hipStream_t stream) {
  const float* Q  = (const float*)d_in[0];
  const float* K  = (const float*)d_in[1];
  const float* V  = (const float*)d_in[2];
  const float* Qp = (const float*)d_in[3];
  const float* Kp = (const float*)d_in[4];
  float* out = (float*)d_out;

  const size_t nKc = (size_t)BH_ * S_ * DQK;   // 8.39M u16
  const size_t nVt = (size_t)BH_ * S_ * D_;    // 4.19M u16
  const size_t nO1 = (size_t)65536 * D_;       // per-split O partial (f32)
  const size_t need2 = 2 * (nO1 + 65536) * 4 + (nKc + nVt) * 2;  // ~59.3 MB

  if (ws_size >= need2) {
    float* Opart = (float*)d_ws;
    float* lpart = Opart + 2 * nO1;
    u16* Kc = (u16*)(lpart + 2 * 65536);
    u16* Vt = Kc + nKc;
    prep_kernel<<<dim3(4096 + 1024), dim3(256), 0, stream>>>(K, V, Kp, Kc, Vt);
    fa5_kernel<1><<<dim3(S_ / BQ, BH_, 2), dim3(256), 0, stream>>>(Q, Qp, Kc, Vt, nullptr, Opart, lpart);
    combine_kernel<<<dim3(4096), dim3(256), 0, stream>>>(Opart, lpart, out);
  } else {
    u16* Kc = (u16*)d_ws;
    u16* Vt = Kc + nKc;
    prep_kernel<<<dim3(4096 + 1024), dim3(256), 0, stream>>>(K, V, Kp, Kc, Vt);
    fa5_kernel<0><<<dim3(S_ / BQ, BH_, 1), dim3(256), 0, stream>>>(Q, Qp, Kc, Vt, out, nullptr, nullptr);
  }
}

// Round 6
// 246.630 us; speedup vs baseline: 1.0665x; 1.0665x over previous
//
#include <hip/hip_runtime.h>

#define BH_ 32
#define S_ 2048
#define D_ 64
#define DQK 128
#define BQ 128   // q rows per block (4 waves x 32 q-rows each)
#define BK 64    // kv rows per tile

typedef unsigned short u16;
typedef u16 u16x4 __attribute__((ext_vector_type(4)));
typedef u16 u16x8 __attribute__((ext_vector_type(8)));
typedef __bf16 bf16x8 __attribute__((ext_vector_type(8)));
typedef float f32x4 __attribute__((ext_vector_type(4)));

__device__ __forceinline__ u16 f2bf_rne(float f) {
  unsigned u = __builtin_bit_cast(unsigned, f);
  u += 0x7fffu + ((u >> 16) & 1u);
  return (u16)(u >> 16);
}
__device__ __forceinline__ u16 f2bf_fast(float f) {  // round-half-up
  unsigned u = __builtin_bit_cast(unsigned, f);
  u += 0x8000u;
  return (u16)(u >> 16);
}
__device__ __forceinline__ bf16x8 ld8(const u16* p) {
  return __builtin_bit_cast(bf16x8, *(const u16x8*)p);
}

// LDS-only barrier: does NOT drain vmcnt -> prefetch global loads stay in flight
#define BARRIER_LGKM() asm volatile("s_waitcnt lgkmcnt(0)\n\ts_barrier" ::: "memory")

#define COEF 0.1803368801111204f  // (1/8) * log2(e), folded into Q conversion

// ---------------- prep: Kc = bf16 [K|Kp] concat; Vt = bf16 V-transposed ----
__global__ __launch_bounds__(256)
void prep_kernel(const float* __restrict__ K, const float* __restrict__ V,
                 const float* __restrict__ Kp,
                 u16* __restrict__ Kc, u16* __restrict__ Vt) {
  __shared__ float Ls[64][65];
  int b = blockIdx.x;
  if (b < 4096) {
    int t = b * 256 + threadIdx.x;          // 1,048,576 threads x 8 elems
    int col8 = (t & 15) * 8;
    int s    = (t >> 4) & 2047;
    int bh   = t >> 15;
    const float* src = (col8 < 64) ? (K  + ((size_t)bh * S_ + s) * D_ + col8)
                                   : (Kp + ((size_t)bh * S_ + s) * D_ + (col8 - 64));
    float4 v0 = *(const float4*)src;
    float4 v1 = *(const float4*)(src + 4);
    u16x8 w;
    w[0] = f2bf_rne(v0.x); w[1] = f2bf_rne(v0.y); w[2] = f2bf_rne(v0.z); w[3] = f2bf_rne(v0.w);
    w[4] = f2bf_rne(v1.x); w[5] = f2bf_rne(v1.y); w[6] = f2bf_rne(v1.z); w[7] = f2bf_rne(v1.w);
    *(u16x8*)(Kc + ((size_t)bh * S_ + s) * DQK + col8) = w;
  } else {
    int id = b - 4096;
    int bh = id >> 5, kt = id & 31;
    int tid = threadIdx.x;
    #pragma unroll
    for (int it = 0; it < 4; ++it) {
      int i = it * 256 + tid;
      int kv = i >> 4, dg = (i & 15) * 4;
      float4 v = *(const float4*)(V + ((size_t)bh * S_ + kt * 64 + kv) * D_ + dg);
      Ls[kv][dg + 0] = v.x; Ls[kv][dg + 1] = v.y;
      Ls[kv][dg + 2] = v.z; Ls[kv][dg + 3] = v.w;
    }
    __syncthreads();
    int d = tid >> 2, kvg = (tid & 3) * 16;
    u16x8 w0, w1;
    #pragma unroll
    for (int j = 0; j < 8; ++j) w0[j] = f2bf_rne(Ls[kvg + j][d]);
    #pragma unroll
    for (int j = 0; j < 8; ++j) w1[j] = f2bf_rne(Ls[kvg + 8 + j][d]);
    u16* dst = Vt + (((size_t)bh * 32 + kt) * 64 + d) * 64 + kvg;
    *(u16x8*)dst = w0;
    *(u16x8*)(dst + 8) = w1;
  }
}

// ---------------- flash-attention main kernel -----------------------------
// S^T = Kc.Qc^T (Q register-held B operand). XOR-swizzled 40960 B LDS
// (3 blocks/CU). Register prefetch with EXPLICIT named u16x8 scalars
// (no lambdas/arrays -> no scratch spill). lgkm-only barriers keep
// prefetch global loads in flight across the barrier.
template <int SPLIT>
__global__ __launch_bounds__(256, 3)
void fa6_kernel(const float* __restrict__ Q, const float* __restrict__ Qp,
                const u16* __restrict__ Kc, const u16* __restrict__ Vtg,
                float* __restrict__ out, float* __restrict__ Opart,
                float* __restrict__ lpart) {
  __shared__ alignas(16) u16 Ks[64 * 128];   // row*128 + ((ch^row)*8), ch 0..15
  __shared__ alignas(16) u16 Vt[64 * 64];    // row*64  + ((ch^(row&7))*8), ch 0..7
  __shared__ alignas(16) u16 Ps[128 * 64];   // row*64  + ((ch^(row&7))*8)

  const int tid  = threadIdx.x;
  const int wave = tid >> 6;
  const int lane = tid & 63;
  const int quad = lane >> 4;
  const int l16  = lane & 15;
  const int m0   = wave * 32;

  const int bh = blockIdx.y;
  const int q0 = blockIdx.x * BQ;
  const int kz = SPLIT ? blockIdx.z : 0;
  const int NZ = SPLIT ? gridDim.z : 1;
  const int kt_b = kz * 32 / NZ;
  const int kt_e = (kz + 1) * 32 / NZ;

  // ---- Q B-frags in registers, softmax scale folded into the conversion ----
  bf16x8 bq0_0, bq0_1, bq0_2, bq0_3, bq1_0, bq1_1, bq1_2, bq1_3;
  {
    #define LOADQ(DST, NQ, KS)                                                  \
      {                                                                         \
        const float* base_ = ((KS) < 2 ? Q : Qp)                                \
            + ((size_t)bh * S_ + q0 + m0 + (NQ) * 16 + l16) * D_                \
            + ((KS) & 1) * 32 + quad * 8;                                       \
        float4 v0_ = *(const float4*)base_;                                     \
        float4 v1_ = *(const float4*)(base_ + 4);                               \
        u16x8 w_;                                                               \
        w_[0] = f2bf_rne(v0_.x * COEF); w_[1] = f2bf_rne(v0_.y * COEF);         \
        w_[2] = f2bf_rne(v0_.z * COEF); w_[3] = f2bf_rne(v0_.w * COEF);         \
        w_[4] = f2bf_rne(v1_.x * COEF); w_[5] = f2bf_rne(v1_.y * COEF);         \
        w_[6] = f2bf_rne(v1_.z * COEF); w_[7] = f2bf_rne(v1_.w * COEF);         \
        DST = __builtin_bit_cast(bf16x8, w_);                                   \
      }
    LOADQ(bq0_0, 0, 0) LOADQ(bq0_1, 0, 1) LOADQ(bq0_2, 0, 2) LOADQ(bq0_3, 0, 3)
    LOADQ(bq1_0, 1, 0) LOADQ(bq1_1, 1, 1) LOADQ(bq1_2, 1, 2) LOADQ(bq1_3, 1, 3)
    #undef LOADQ
  }

  f32x4 acc00 = {0.f,0.f,0.f,0.f}, acc01 = {0.f,0.f,0.f,0.f};
  f32x4 acc02 = {0.f,0.f,0.f,0.f}, acc03 = {0.f,0.f,0.f,0.f};
  f32x4 acc10 = {0.f,0.f,0.f,0.f}, acc11 = {0.f,0.f,0.f,0.f};
  f32x4 acc12 = {0.f,0.f,0.f,0.f}, acc13 = {0.f,0.f,0.f,0.f};
  float l_part0 = 0.f, l_part1 = 0.f;

  // thread-constant staging decode
  const int krow0 = tid >> 4, kch = tid & 15;   // K rows: krow0, +16, +32, +48
  const int vrow0 = tid >> 3, vch = tid & 7;    // V rows: vrow0, +32
  const u16* kbase = Kc + ((size_t)bh * S_ + krow0) * DQK + kch * 8;
  const u16* vbase = Vtg + ((size_t)bh * 32 * 64 + vrow0) * 64 + vch * 8;
  u16* const ksw0 = &Ks[krow0 * 128 + ((kch ^ krow0) << 3)];            // krow0&15==krow0
  u16* const vsw0 = &Vt[(vrow0 << 6) + ((vch ^ (vrow0 & 7)) << 3)];

  #define LOAD_TILE(KT, A0, A1, A2, A3, B0, B1)                                 \
    {                                                                           \
      const u16* kp_ = kbase + (size_t)(KT) * 64 * DQK;                         \
      A0 = *(const u16x8*)(kp_);                                                \
      A1 = *(const u16x8*)(kp_ + 16 * DQK);                                     \
      A2 = *(const u16x8*)(kp_ + 32 * DQK);                                     \
      A3 = *(const u16x8*)(kp_ + 48 * DQK);                                     \
      const u16* vp_ = vbase + (size_t)(KT) * 64 * 64;                          \
      B0 = *(const u16x8*)(vp_);                                                \
      B1 = *(const u16x8*)(vp_ + 32 * 64);                                      \
    }

  #define STORE_LDS(A0, A1, A2, A3, B0, B1)                                     \
    {                                                                           \
      *(u16x8*)(ksw0)             = A0;                                         \
      *(u16x8*)(ksw0 + 16 * 128)  = A1;                                         \
      *(u16x8*)(ksw0 + 32 * 128)  = A2;                                         \
      *(u16x8*)(ksw0 + 48 * 128)  = A3;                                         \
      *(u16x8*)(vsw0)             = B0;                                         \
      *(u16x8*)(vsw0 + 32 * 64)   = B1;                                         \
    }

  #define COMPUTE_TILE()                                                        \
    {                                                                           \
      _Pragma("unroll")                                                         \
      for (int mt = 0; mt < 4; ++mt) {                                          \
        f32x4 s0 = {0.f,0.f,0.f,0.f};                                           \
        f32x4 s1 = {0.f,0.f,0.f,0.f};                                           \
        bf16x8 ak;                                                              \
        ak = ld8(&Ks[(mt * 16 + l16) * 128 + (((0 * 4 + quad) ^ l16) << 3)]);   \
        s0 = __builtin_amdgcn_mfma_f32_16x16x32_bf16(ak, bq0_0, s0, 0, 0, 0);   \
        s1 = __builtin_amdgcn_mfma_f32_16x16x32_bf16(ak, bq1_0, s1, 0, 0, 0);   \
        ak = ld8(&Ks[(mt * 16 + l16) * 128 + (((1 * 4 + quad) ^ l16) << 3)]);   \
        s0 = __builtin_amdgcn_mfma_f32_16x16x32_bf16(ak, bq0_1, s0, 0, 0, 0);   \
        s1 = __builtin_amdgcn_mfma_f32_16x16x32_bf16(ak, bq1_1, s1, 0, 0, 0);   \
        ak = ld8(&Ks[(mt * 16 + l16) * 128 + (((2 * 4 + quad) ^ l16) << 3)]);   \
        s0 = __builtin_amdgcn_mfma_f32_16x16x32_bf16(ak, bq0_2, s0, 0, 0, 0);   \
        s1 = __builtin_amdgcn_mfma_f32_16x16x32_bf16(ak, bq1_2, s1, 0, 0, 0);   \
        ak = ld8(&Ks[(mt * 16 + l16) * 128 + (((3 * 4 + quad) ^ l16) << 3)]);   \
        s0 = __builtin_amdgcn_mfma_f32_16x16x32_bf16(ak, bq0_3, s0, 0, 0, 0);   \
        s1 = __builtin_amdgcn_mfma_f32_16x16x32_bf16(ak, bq1_3, s1, 0, 0, 0);   \
        u16x4 w0, w1;                                                           \
        float rs0 = 0.f, rs1 = 0.f;                                             \
        _Pragma("unroll")                                                       \
        for (int r = 0; r < 4; ++r) {                                           \
          float p0 = exp2f(s0[r]);                                              \
          float p1 = exp2f(s1[r]);                                              \
          w0[r] = f2bf_fast(p0); w1[r] = f2bf_fast(p1);                         \
          rs0 += p0; rs1 += p1;                                                 \
        }                                                                       \
        l_part0 += rs0; l_part1 += rs1;                                         \
        const int chs = ((mt * 2 + (quad >> 1)) ^ (l16 & 7)) << 3;              \
        const int sub = (quad & 1) << 2;                                        \
        *(u16x4*)&Ps[((m0 + l16) << 6) + chs + sub]      = w0;                  \
        *(u16x4*)&Ps[((m0 + 16 + l16) << 6) + chs + sub] = w1;                  \
      }                                                                         \
      bf16x8 pa00 = ld8(&Ps[((m0 + l16) << 6)      + (((0 + quad) ^ (l16 & 7)) << 3)]); \
      bf16x8 pa01 = ld8(&Ps[((m0 + l16) << 6)      + (((4 + quad) ^ (l16 & 7)) << 3)]); \
      bf16x8 pa10 = ld8(&Ps[((m0 + 16 + l16) << 6) + (((0 + quad) ^ (l16 & 7)) << 3)]); \
      bf16x8 pa11 = ld8(&Ps[((m0 + 16 + l16) << 6) + (((4 + quad) ^ (l16 & 7)) << 3)]); \
      _Pragma("unroll")                                                         \
      for (int ntd = 0; ntd < 4; ++ntd) {                                       \
        bf16x8 bv0 = ld8(&Vt[((ntd * 16 + l16) << 6) + (((0 + quad) ^ (l16 & 7)) << 3)]); \
        bf16x8 bv1 = ld8(&Vt[((ntd * 16 + l16) << 6) + (((4 + quad) ^ (l16 & 7)) << 3)]); \
        f32x4* a0 = (ntd == 0) ? &acc00 : (ntd == 1) ? &acc01 : (ntd == 2) ? &acc02 : &acc03; \
        f32x4* a1 = (ntd == 0) ? &acc10 : (ntd == 1) ? &acc11 : (ntd == 2) ? &acc12 : &acc13; \
        *a0 = __builtin_amdgcn_mfma_f32_16x16x32_bf16(pa00, bv0, *a0, 0, 0, 0); \
        *a0 = __builtin_amdgcn_mfma_f32_16x16x32_bf16(pa01, bv1, *a0, 0, 0, 0); \
        *a1 = __builtin_amdgcn_mfma_f32_16x16x32_bf16(pa10, bv0, *a1, 0, 0, 0); \
        *a1 = __builtin_amdgcn_mfma_f32_16x16x32_bf16(pa11, bv1, *a1, 0, 0, 0); \
      }                                                                         \
    }

  // explicit double-buffered pipeline, no arrays, no lambdas
  u16x8 xa0, xa1, xa2, xa3, ya0, ya1;
  u16x8 xb0, xb1, xb2, xb3, yb0, yb1;
  LOAD_TILE(kt_b, xa0, xa1, xa2, xa3, ya0, ya1);
  for (int kt = kt_b; kt < kt_e; kt += 2) {
    STORE_LDS(xa0, xa1, xa2, xa3, ya0, ya1);
    const bool h1 = (kt + 1 < kt_e);
    if (h1) LOAD_TILE(kt + 1, xb0, xb1, xb2, xb3, yb0, yb1);
    BARRIER_LGKM();
    COMPUTE_TILE();
    BARRIER_LGKM();
    if (h1) {
      STORE_LDS(xb0, xb1, xb2, xb3, yb0, yb1);
      if (kt + 2 < kt_e) LOAD_TILE(kt + 2, xa0, xa1, xa2, xa3, ya0, ya1);
      BARRIER_LGKM();
      COMPUTE_TILE();
      BARRIER_LGKM();
    }
  }
  #undef LOAD_TILE
  #undef STORE_LDS
  #undef COMPUTE_TILE

  // ---- epilogue ----
  float lsum0 = l_part0, lsum1 = l_part1;
  lsum0 += __shfl_xor(lsum0, 16); lsum0 += __shfl_xor(lsum0, 32);
  lsum1 += __shfl_xor(lsum1, 16); lsum1 += __shfl_xor(lsum1, 32);

  f32x4 accA[2][4] = {{acc00, acc01, acc02, acc03}, {acc10, acc11, acc12, acc13}};
  if (SPLIT) {
    #pragma unroll
    for (int mtq = 0; mtq < 2; ++mtq)
      #pragma unroll
      for (int r = 0; r < 4; ++r) {
        size_t rowb = ((size_t)kz * 65536 + (size_t)bh * S_
                       + q0 + m0 + mtq * 16 + quad * 4 + r) * D_;
        #pragma unroll
        for (int ntd = 0; ntd < 4; ++ntd)
          Opart[rowb + ntd * 16 + l16] = accA[mtq][ntd][r];
      }
    if (quad == 0) {
      lpart[(size_t)kz * 65536 + (size_t)bh * S_ + q0 + m0 + l16]      = lsum0;
      lpart[(size_t)kz * 65536 + (size_t)bh * S_ + q0 + m0 + 16 + l16] = lsum1;
    }
  } else {
    #pragma unroll
    for (int mtq = 0; mtq < 2; ++mtq)
      #pragma unroll
      for (int r = 0; r < 4; ++r) {
        float inv = 1.0f / __shfl(mtq ? lsum1 : lsum0, quad * 4 + r);
        size_t rowb = ((size_t)bh * S_ + q0 + m0 + mtq * 16 + quad * 4 + r) * D_;
        #pragma unroll
        for (int ntd = 0; ntd < 4; ++ntd)
          out[rowb + ntd * 16 + l16] = accA[mtq][ntd][r] * inv;
      }
  }
}

// ---------------- combine: out = sum(O_kz) / sum(l_kz) --------------------
template <int NS>
__global__ __launch_bounds__(256)
void combine_kernel(const float* __restrict__ Opart, const float* __restrict__ lpart,
                    float* __restrict__ out) {
  int t = blockIdx.x * 256 + threadIdx.x;   // 1,048,576 threads
  int row = t >> 4;
  int d4  = (t & 15) * 4;
  const size_t NO = (size_t)65536 * D_;
  float4 o = {0.f, 0.f, 0.f, 0.f};
  float l = 0.f;
  #pragma unroll
  for (int kz = 0; kz < NS; ++kz) {
    float4 p = *(const float4*)(Opart + kz * NO + (size_t)row * D_ + d4);
    o.x += p.x; o.y += p.y; o.z += p.z; o.w += p.w;
    l += lpart[kz * 65536 + row];
  }
  float inv = 1.0f / l;
  o.x *= inv; o.y *= inv; o.z *= inv; o.w *= inv;
  *(float4*)(out + (size_t)row * D_ + d4) = o;
}

extern "C" void kernel_launch(void* const* d_in, const int* in_sizes, int n_in,
                              void* d_out, int out_size, void* d_ws, size_t ws_size,
                              hipStream_t stream) {
  const float* Q  = (const float*)d_in[0];
  const float* K  = (const float*)d_in[1];
  const float* V  = (const float*)d_in[2];
  const float* Qp = (const float*)d_in[3];
  const float* Kp = (const float*)d_in[4];
  float* out = (float*)d_out;

  const size_t nKc = (size_t)BH_ * S_ * DQK;   // 8.39M u16
  const size_t nVt = (size_t)BH_ * S_ * D_;    // 4.19M u16
  const size_t nO1 = (size_t)65536 * D_;       // per-split O partial (f32)
  const size_t need3 = 3 * (nO1 + 65536) * 4 + (nKc + nVt) * 2;  // ~76.3 MB
  const size_t need2 = 2 * (nO1 + 65536) * 4 + (nKc + nVt) * 2;  // ~59.3 MB

  if (ws_size >= need3) {
    float* Opart = (float*)d_ws;
    float* lpart = Opart + 3 * nO1;
    u16* Kc = (u16*)(lpart + 3 * 65536);
    u16* Vt = Kc + nKc;
    prep_kernel<<<dim3(4096 + 1024), dim3(256), 0, stream>>>(K, V, Kp, Kc, Vt);
    fa6_kernel<1><<<dim3(S_ / BQ, BH_, 3), dim3(256), 0, stream>>>(Q, Qp, Kc, Vt, nullptr, Opart, lpart);
    combine_kernel<3><<<dim3(4096), dim3(256), 0, stream>>>(Opart, lpart, out);
  } else if (ws_size >= need2) {
    float* Opart = (float*)d_ws;
    float* lpart = Opart + 2 * nO1;
    u16* Kc = (u16*)(lpart + 2 * 65536);
    u16* Vt = Kc + nKc;
    prep_kernel<<<dim3(4096 + 1024), dim3(256), 0, stream>>>(K, V, Kp, Kc, Vt);
    fa6_kernel<1><<<dim3(S_ / BQ, BH_, 2), dim3(256), 0, stream>>>(Q, Qp, Kc, Vt, nullptr, Opart, lpart);
    combine_kernel<2><<<dim3(4096), dim3(256), 0, stream>>>(Opart, lpart, out);
  } else {
    u16* Kc = (u16*)d_ws;
    u16* Vt = Kc + nKc;
    prep_kernel<<<dim3(4096 + 1024), dim3(256), 0, stream>>>(K, V, Kp, Kc, Vt);
    fa6_kernel<0><<<dim3(S_ / BQ, BH_, 1), dim3(256), 0, stream>>>(Q, Qp, Kc, Vt, out, nullptr, nullptr);
  }
}

// Round 7
// 235.013 us; speedup vs baseline: 1.1192x; 1.0494x over previous
//
#include <hip/hip_runtime.h>

#define BH_ 32
#define S_ 2048
#define D_ 64
#define DQK 128
#define BQ 128   // q rows per block (4 waves x 32 q-rows each)
#define BK 64    // kv rows per tile

typedef unsigned short u16;
typedef u16 u16x4 __attribute__((ext_vector_type(4)));
typedef u16 u16x8 __attribute__((ext_vector_type(8)));
typedef __bf16 bf16x8 __attribute__((ext_vector_type(8)));
typedef float f32x4 __attribute__((ext_vector_type(4)));

__device__ __forceinline__ u16 f2bf_rne(float f) {
  unsigned u = __builtin_bit_cast(unsigned, f);
  u += 0x7fffu + ((u >> 16) & 1u);
  return (u16)(u >> 16);
}
__device__ __forceinline__ u16 f2bf_fast(float f) {  // round-half-up
  unsigned u = __builtin_bit_cast(unsigned, f);
  u += 0x8000u;
  return (u16)(u >> 16);
}
__device__ __forceinline__ bf16x8 ld8(const u16* p) {
  return __builtin_bit_cast(bf16x8, *(const u16x8*)p);
}

#define COEF 0.1803368801111204f  // (1/8) * log2(e), folded into Q conversion

// ---------------- prep: Kc = bf16 [K|Kp] concat; Vt = bf16 V-transposed ----
__global__ __launch_bounds__(256)
void prep_kernel(const float* __restrict__ K, const float* __restrict__ V,
                 const float* __restrict__ Kp,
                 u16* __restrict__ Kc, u16* __restrict__ Vt) {
  __shared__ float Ls[64][65];
  int b = blockIdx.x;
  if (b < 4096) {
    int t = b * 256 + threadIdx.x;          // 1,048,576 threads x 8 elems
    int col8 = (t & 15) * 8;
    int s    = (t >> 4) & 2047;
    int bh   = t >> 15;
    const float* src = (col8 < 64) ? (K  + ((size_t)bh * S_ + s) * D_ + col8)
                                   : (Kp + ((size_t)bh * S_ + s) * D_ + (col8 - 64));
    float4 v0 = *(const float4*)src;
    float4 v1 = *(const float4*)(src + 4);
    u16x8 w;
    w[0] = f2bf_rne(v0.x); w[1] = f2bf_rne(v0.y); w[2] = f2bf_rne(v0.z); w[3] = f2bf_rne(v0.w);
    w[4] = f2bf_rne(v1.x); w[5] = f2bf_rne(v1.y); w[6] = f2bf_rne(v1.z); w[7] = f2bf_rne(v1.w);
    *(u16x8*)(Kc + ((size_t)bh * S_ + s) * DQK + col8) = w;
  } else {
    int id = b - 4096;
    int bh = id >> 5, kt = id & 31;
    int tid = threadIdx.x;
    #pragma unroll
    for (int it = 0; it < 4; ++it) {
      int i = it * 256 + tid;
      int kv = i >> 4, dg = (i & 15) * 4;
      float4 v = *(const float4*)(V + ((size_t)bh * S_ + kt * 64 + kv) * D_ + dg);
      Ls[kv][dg + 0] = v.x; Ls[kv][dg + 1] = v.y;
      Ls[kv][dg + 2] = v.z; Ls[kv][dg + 3] = v.w;
    }
    __syncthreads();
    int d = tid >> 2, kvg = (tid & 3) * 16;
    u16x8 w0, w1;
    #pragma unroll
    for (int j = 0; j < 8; ++j) w0[j] = f2bf_rne(Ls[kvg + j][d]);
    #pragma unroll
    for (int j = 0; j < 8; ++j) w1[j] = f2bf_rne(Ls[kvg + 8 + j][d]);
    u16* dst = Vt + (((size_t)bh * 32 + kt) * 64 + d) * 64 + kvg;
    *(u16x8*)dst = w0;
    *(u16x8*)(dst + 8) = w1;
  }
}

// ---------------- flash-attention main kernel -----------------------------
// fa3 structure (direct global->LDS staging, __syncthreads) + XOR-swizzled
// unpadded LDS: 40960 B -> 3 blocks/CU. S^T = Kc.Qc^T, Q register-held.
template <int SPLIT>
__global__ __launch_bounds__(256, 3)
void fa7_kernel(const float* __restrict__ Q, const float* __restrict__ Qp,
                const u16* __restrict__ Kc, const u16* __restrict__ Vtg,
                float* __restrict__ out, float* __restrict__ Opart,
                float* __restrict__ lpart) {
  __shared__ alignas(16) u16 Ks[64 * 128];   // row*128 + ((ch^(row&15))*8)
  __shared__ alignas(16) u16 Vt[64 * 64];    // row*64  + ((ch^(row&7))*8)
  __shared__ alignas(16) u16 Ps[128 * 64];   // row*64  + ((ch^(row&7))*8)

  const int tid  = threadIdx.x;
  const int wave = tid >> 6;
  const int lane = tid & 63;
  const int quad = lane >> 4;
  const int l16  = lane & 15;
  const int m0   = wave * 32;

  const int bh = blockIdx.y;
  const int q0 = blockIdx.x * BQ;
  const int kz = SPLIT ? blockIdx.z : 0;
  const int kt_b = SPLIT ? kz * 16 : 0;
  const int kt_e = SPLIT ? kt_b + 16 : 32;

  // ---- Q B-frags in registers, softmax scale folded into the conversion ----
  bf16x8 bq[2][4];
  #pragma unroll
  for (int nq = 0; nq < 2; ++nq)
    #pragma unroll
    for (int ks = 0; ks < 4; ++ks) {
      const float* base = (ks < 2 ? Q : Qp)
          + ((size_t)bh * S_ + q0 + m0 + nq * 16 + l16) * D_ + (ks & 1) * 32 + quad * 8;
      float4 v0 = *(const float4*)base;
      float4 v1 = *(const float4*)(base + 4);
      u16x8 w;
      w[0] = f2bf_rne(v0.x * COEF); w[1] = f2bf_rne(v0.y * COEF);
      w[2] = f2bf_rne(v0.z * COEF); w[3] = f2bf_rne(v0.w * COEF);
      w[4] = f2bf_rne(v1.x * COEF); w[5] = f2bf_rne(v1.y * COEF);
      w[6] = f2bf_rne(v1.z * COEF); w[7] = f2bf_rne(v1.w * COEF);
      bq[nq][ks] = __builtin_bit_cast(bf16x8, w);
    }

  f32x4 acc[2][4];
  float l_part[2] = {0.f, 0.f};
  #pragma unroll
  for (int mtq = 0; mtq < 2; ++mtq)
    #pragma unroll
    for (int nt = 0; nt < 4; ++nt) acc[mtq][nt] = (f32x4){0.f, 0.f, 0.f, 0.f};

  for (int kt = kt_b; kt < kt_e; ++kt) {
    __syncthreads();
    // stage K-cat tile: 64 x 128 bf16, swizzled write
    #pragma unroll
    for (int it = 0; it < 4; ++it) {
      int i = it * 256 + tid, row = i >> 4, ch = i & 15;
      u16x8 v = *(const u16x8*)(Kc + ((size_t)bh * S_ + kt * 64 + row) * DQK + ch * 8);
      *(u16x8*)&Ks[row * 128 + ((ch ^ (row & 15)) << 3)] = v;
    }
    // stage Vt tile: 64(d) x 64(kv), swizzled write
    #pragma unroll
    for (int it = 0; it < 2; ++it) {
      int i = it * 256 + tid, row = i >> 3, ch = i & 7;
      u16x8 v = *(const u16x8*)(Vtg + (((size_t)bh * 32 + kt) * 64 + row) * 64 + ch * 8);
      *(u16x8*)&Vt[(row << 6) + ((ch ^ (row & 7)) << 3)] = v;
    }
    __syncthreads();

    // ---- S^T = Ks . Qc^T : m = kv (4 x 16), n = q (2 x 16 per wave) ----
    #pragma unroll
    for (int mt = 0; mt < 4; ++mt) {
      f32x4 s0 = (f32x4){0.f, 0.f, 0.f, 0.f};
      f32x4 s1 = (f32x4){0.f, 0.f, 0.f, 0.f};
      #pragma unroll
      for (int ks = 0; ks < 4; ++ks) {
        bf16x8 ak = ld8(&Ks[(mt * 16 + l16) * 128 + (((ks * 4 + quad) ^ l16) << 3)]);
        s0 = __builtin_amdgcn_mfma_f32_16x16x32_bf16(ak, bq[0][ks], s0, 0, 0, 0);
        s1 = __builtin_amdgcn_mfma_f32_16x16x32_bf16(ak, bq[1][ks], s1, 0, 0, 0);
      }
      // C layout: row = kv = quad*4+r, col = q = l16. exp + swizzled b64 P-write.
      u16x4 w0, w1;
      float rs0 = 0.f, rs1 = 0.f;
      #pragma unroll
      for (int r = 0; r < 4; ++r) {
        float p0 = exp2f(s0[r]);
        float p1 = exp2f(s1[r]);
        w0[r] = f2bf_fast(p0); w1[r] = f2bf_fast(p1);
        rs0 += p0; rs1 += p1;
      }
      l_part[0] += rs0; l_part[1] += rs1;
      const int chs = ((mt * 2 + (quad >> 1)) ^ (l16 & 7)) << 3;
      const int sub = (quad & 1) << 2;
      *(u16x4*)&Ps[((m0 + l16) << 6) + chs + sub]      = w0;
      *(u16x4*)&Ps[((m0 + 16 + l16) << 6) + chs + sub] = w1;
    }

    // ---- O += P . V ----
    bf16x8 pa[2][2];
    #pragma unroll
    for (int mtq = 0; mtq < 2; ++mtq)
      #pragma unroll
      for (int ks = 0; ks < 2; ++ks)
        pa[mtq][ks] = ld8(&Ps[((m0 + mtq * 16 + l16) << 6) + (((ks * 4 + quad) ^ (l16 & 7)) << 3)]);
    #pragma unroll
    for (int ntd = 0; ntd < 4; ++ntd) {
      #pragma unroll
      for (int ks = 0; ks < 2; ++ks) {
        bf16x8 bv = ld8(&Vt[((ntd * 16 + l16) << 6) + (((ks * 4 + quad) ^ (l16 & 7)) << 3)]);
        acc[0][ntd] = __builtin_amdgcn_mfma_f32_16x16x32_bf16(pa[0][ks], bv, acc[0][ntd], 0, 0, 0);
        acc[1][ntd] = __builtin_amdgcn_mfma_f32_16x16x32_bf16(pa[1][ks], bv, acc[1][ntd], 0, 0, 0);
      }
    }
  }

  // ---- epilogue ----
  float lsum[2];
  #pragma unroll
  for (int nq = 0; nq < 2; ++nq) {
    float v = l_part[nq];
    v += __shfl_xor(v, 16);
    v += __shfl_xor(v, 32);
    lsum[nq] = v;  // lane holds l for q = nq*16 + l16 (this block's kv range)
  }

  if (SPLIT) {
    #pragma unroll
    for (int mtq = 0; mtq < 2; ++mtq)
      #pragma unroll
      for (int r = 0; r < 4; ++r) {
        size_t rowb = ((size_t)kz * 65536 + (size_t)bh * S_
                       + q0 + m0 + mtq * 16 + quad * 4 + r) * D_;
        #pragma unroll
        for (int ntd = 0; ntd < 4; ++ntd)
          Opart[rowb + ntd * 16 + l16] = acc[mtq][ntd][r];
      }
    if (quad == 0) {
      #pragma unroll
      for (int nq = 0; nq < 2; ++nq)
        lpart[(size_t)kz * 65536 + (size_t)bh * S_ + q0 + m0 + nq * 16 + l16] = lsum[nq];
    }
  } else {
    #pragma unroll
    for (int mtq = 0; mtq < 2; ++mtq)
      #pragma unroll
      for (int r = 0; r < 4; ++r) {
        float inv = 1.0f / __shfl(lsum[mtq], quad * 4 + r);
        size_t rowb = ((size_t)bh * S_ + q0 + m0 + mtq * 16 + quad * 4 + r) * D_;
        #pragma unroll
        for (int ntd = 0; ntd < 4; ++ntd)
          out[rowb + ntd * 16 + l16] = acc[mtq][ntd][r] * inv;
      }
  }
}

// ---------------- combine: out = (O0 + O1) / (l0 + l1) --------------------
__global__ __launch_bounds__(256)
void combine_kernel(const float* __restrict__ Opart, const float* __restrict__ lpart,
                    float* __restrict__ out) {
  int t = blockIdx.x * 256 + threadIdx.x;   // 1,048,576 threads
  int row = t >> 4;
  int d4  = (t & 15) * 4;
  const size_t NO = (size_t)65536 * D_;
  float4 o0 = *(const float4*)(Opart + (size_t)row * D_ + d4);
  float4 o1 = *(const float4*)(Opart + NO + (size_t)row * D_ + d4);
  float inv = 1.0f / (lpart[row] + lpart[65536 + row]);
  float4 o;
  o.x = (o0.x + o1.x) * inv; o.y = (o0.y + o1.y) * inv;
  o.z = (o0.z + o1.z) * inv; o.w = (o0.w + o1.w) * inv;
  *(float4*)(out + (size_t)row * D_ + d4) = o;
}

extern "C" void kernel_launch(void* const* d_in, const int* in_sizes, int n_in,
                              void* d_out, int out_size, void* d_ws, size_t ws_size,
                              hipStream_t stream) {
  const float* Q  = (const float*)d_in[0];
  const float* K  = (const float*)d_in[1];
  const float* V  = (const float*)d_in[2];
  const float* Qp = (const float*)d_in[3];
  const float* Kp = (const float*)d_in[4];
  float* out = (float*)d_out;

  const size_t nKc = (size_t)BH_ * S_ * DQK;   // 8.39M u16
  const size_t nVt = (size_t)BH_ * S_ * D_;    // 4.19M u16
  const size_t nO1 = (size_t)65536 * D_;       // per-split O partial (f32)
  const size_t need2 = 2 * (nO1 + 65536) * 4 + (nKc + nVt) * 2;  // ~59.3 MB

  if (ws_size >= need2) {
    float* Opart = (float*)d_ws;
    float* lpart = Opart + 2 * nO1;
    u16* Kc = (u16*)(lpart + 2 * 65536);
    u16* Vt = Kc + nKc;
    prep_kernel<<<dim3(4096 + 1024), dim3(256), 0, stream>>>(K, V, Kp, Kc, Vt);
    fa7_kernel<1><<<dim3(S_ / BQ, BH_, 2), dim3(256), 0, stream>>>(Q, Qp, Kc, Vt, nullptr, Opart, lpart);
    combine_kernel<<<dim3(4096), dim3(256), 0, stream>>>(Opart, lpart, out);
  } else {
    u16* Kc = (u16*)d_ws;
    u16* Vt = Kc + nKc;
    prep_kernel<<<dim3(4096 + 1024), dim3(256), 0, stream>>>(K, V, Kp, Kc, Vt);
    fa7_kernel<0><<<dim3(S_ / BQ, BH_, 1), dim3(256), 0, stream>>>(Q, Qp, Kc, Vt, out, nullptr, nullptr);
  }
}